// Round 6
// baseline (635.987 us; speedup 1.0000x reference)
//
#include <hip/hip_runtime.h>
#include <hip/hip_cooperative_groups.h>
#include <math.h>

namespace cg = cooperative_groups;

#define NBLK 512

using half4 = __attribute__((ext_vector_type(4))) _Float16;
using half8 = __attribute__((ext_vector_type(8))) _Float16;
using f32x4 = __attribute__((ext_vector_type(4))) float;

__device__ __forceinline__ float sigm(float z) { return 1.f / (1.f + __expf(-z)); }

struct ConvArgs {
    const float* src[8];
    _Float16*    dst[8];
    int cum[9];
    int sstr[8];
    int dstr[8];
    int rl[8];
};

struct G3Desc {
    const _Float16* A;
    const _Float16* W;
    const float* bias;
    void* o0;
    void* o1;
    int lda, ldw, mode, nbx;   // mode 0: f16 out; 1: kvsplit; 2: f32 out
};
struct G3Args { G3Desc d[3]; int cum[4]; };

struct FusedArgs {
    ConvArgs ca;
    G3Args   ga;
    // attn + gctx
    const _Float16* q16;
    const _Float16* k16;
    const _Float16* vT16;
    float*          bufC;      // gctx fp32 [8*256][768]
    _Float16*       xg16;      // [2048][1536]; gctx f16 lands at cols 768..
    // gate1
    const _Float16* Wg116;
    const float*    bg1;
    const float*    x;
    float*          bufB;      // h1 fp32
    _Float16*       h116;
    // final
    const _Float16* Wg2a16;
    const float*    bg2;
    const float*    bufE;
    const float*    sIn;
    float*          out;
};

union SharedAll {
    struct { _Float16 As[64][72]; _Float16 Ws[64][72]; } g;            // 18432 B
    union {
        struct { _Float16 As[64][72]; _Float16 Ws[128][72]; } qk;      // 27648 B
        struct { _Float16 Ps[64][136]; _Float16 Vs[64][136]; } pv;     // 34816 B
    } attn;
    struct {
        union { struct { _Float16 As[64][72]; _Float16 Ws[64][72]; } a;
                float Ds[64][76]; } u;                                  // 19456 B
        float Es[32][64];
        float Ss[32][64];                                               // +16384 B
    } fin;                                                              // 35840 B
};

__global__ __launch_bounds__(256, 2) void fused_all(FusedArgs fa) {
    __shared__ SharedAll sh;

    const int t    = threadIdx.x;
    const int w    = t >> 6;
    const int lane = t & 63;
    const int quad = lane >> 4;
    const int l16  = lane & 15;
    const int sr   = t >> 3;          // 0..31
    const int sk   = (t & 7) * 8;     // 0..56

    cg::grid_group grid = cg::this_grid();

    // ================= phase 0: f32 -> f16 conversions =================
    {
        const ConvArgs& a = fa.ca;
        for (int c = blockIdx.x * 256 + t; c < a.cum[8]; c += NBLK * 256) {
            int seg = 0;
            while (c >= a.cum[seg + 1]) ++seg;
            const int lc  = c - a.cum[seg];
            const unsigned cpr = (unsigned)(a.rl[seg] >> 3);
            const unsigned row = (unsigned)lc / cpr;
            const int col = (lc - (int)(row * cpr)) * 8;
            const float* sp = a.src[seg] + (size_t)row * a.sstr[seg] + col;
            float4 v0 = *(const float4*)sp;
            float4 v1 = *(const float4*)(sp + 4);
            half8 h;
            h[0] = (_Float16)v0.x; h[1] = (_Float16)v0.y; h[2] = (_Float16)v0.z; h[3] = (_Float16)v0.w;
            h[4] = (_Float16)v1.x; h[5] = (_Float16)v1.y; h[6] = (_Float16)v1.z; h[7] = (_Float16)v1.w;
            *(half8*)(a.dst[seg] + (size_t)row * a.dstr[seg] + col) = h;
        }
    }
    grid.sync();

    // ================= phase 1: gemm3 (q, kv, E) — 816 tiles ===========
    for (int bid = blockIdx.x; bid < 816; bid += NBLK) {
        int seg = 0;
        while (bid >= fa.ga.cum[seg + 1]) ++seg;
        const G3Desc& d = fa.ga.d[seg];
        const int local = bid - fa.ga.cum[seg];
        const int by    = local / d.nbx;
        const int bx    = local - by * d.nbx;
        const int bm    = by * 64;
        const int bn    = bx * 64;
        const _Float16* A = d.A;
        const _Float16* W = d.W;
        const int lda = d.lda;
        const int ldw = d.ldw;

        f32x4 acc[4] = {};

        half8 av[2], wv[2];
        #pragma unroll
        for (int i = 0; i < 2; ++i) {
            av[i] = *(const half8*)(A + (size_t)(bm + i * 32 + sr) * lda + sk);
            wv[i] = *(const half8*)(W + (size_t)(bn + i * 32 + sr) * ldw + sk);
        }

        for (int k0 = 0; k0 < 768; k0 += 64) {
            __syncthreads();
            #pragma unroll
            for (int i = 0; i < 2; ++i) {
                *(half8*)&sh.g.As[i * 32 + sr][sk] = av[i];
                *(half8*)&sh.g.Ws[i * 32 + sr][sk] = wv[i];
            }
            __syncthreads();
            if (k0 + 64 < 768) {
                #pragma unroll
                for (int i = 0; i < 2; ++i) {
                    av[i] = *(const half8*)(A + (size_t)(bm + i * 32 + sr) * lda + k0 + 64 + sk);
                    wv[i] = *(const half8*)(W + (size_t)(bn + i * 32 + sr) * ldw + k0 + 64 + sk);
                }
            }
            __builtin_amdgcn_sched_barrier(0);
            #pragma unroll
            for (int kk = 0; kk < 2; ++kk) {
                half8 af = *(const half8*)&sh.g.As[w * 16 + l16][kk * 32 + quad * 8];
                #pragma unroll
                for (int j = 0; j < 4; ++j) {
                    half8 bf = *(const half8*)&sh.g.Ws[j * 16 + l16][kk * 32 + quad * 8];
                    acc[j] = __builtin_amdgcn_mfma_f32_16x16x32_f16(af, bf, acc[j], 0, 0, 0);
                }
            }
        }

        const int mode = d.mode;
        const float* bias = d.bias;
        #pragma unroll
        for (int j = 0; j < 4; ++j) {
            const int col  = bn + j * 16 + l16;
            const int row0 = bm + w * 16 + quad * 4;
            const float bv = bias ? bias[col] : 0.f;
            if (mode == 0) {
                _Float16* C2 = (_Float16*)d.o0;
                #pragma unroll
                for (int r = 0; r < 4; ++r)
                    C2[(size_t)(row0 + r) * 768 + col] = (_Float16)(acc[j][r] + bv);
            } else if (mode == 1) {
                _Float16* K16  = (_Float16*)d.o0;
                _Float16* VT16 = (_Float16*)d.o1;
                if (col < 768) {
                    #pragma unroll
                    for (int r = 0; r < 4; ++r)
                        K16[(size_t)(row0 + r) * 768 + col] = (_Float16)(acc[j][r] + bv);
                } else {
                    const int b = row0 >> 7, h = col - 768, m0 = row0 & 127;
                    half4 hv;
                    #pragma unroll
                    for (int r = 0; r < 4; ++r) hv[r] = (_Float16)(acc[j][r] + bv);
                    *(half4*)(VT16 + ((size_t)(b * 768 + h)) * 128 + m0) = hv;
                }
            } else {
                float* C = (float*)d.o0;
                #pragma unroll
                for (int r = 0; r < 4; ++r)
                    C[(size_t)(row0 + r) * 768 + col] = acc[j][r] + bv;
            }
        }
    }
    grid.sync();

    // ======== phase 2: attn scores + softmax + PV (gctx), 32 blocks =====
    if (blockIdx.x < 32) {
        const int z  = blockIdx.x >> 2;
        const int bm = (blockIdx.x & 3) * 64;
        const _Float16* A = fa.q16 + (size_t)z * 256 * 768 + (size_t)bm * 768;
        const _Float16* W = fa.k16 + (size_t)z * 128 * 768;

        f32x4 acc[8] = {};

        half8 av[2], wv[4];
        #pragma unroll
        for (int i = 0; i < 2; ++i)
            av[i] = *(const half8*)(A + (size_t)(i * 32 + sr) * 768 + sk);
        #pragma unroll
        for (int i = 0; i < 4; ++i)
            wv[i] = *(const half8*)(W + (size_t)(i * 32 + sr) * 768 + sk);

        for (int k0 = 0; k0 < 768; k0 += 64) {
            __syncthreads();
            #pragma unroll
            for (int i = 0; i < 2; ++i) *(half8*)&sh.attn.qk.As[i * 32 + sr][sk] = av[i];
            #pragma unroll
            for (int i = 0; i < 4; ++i) *(half8*)&sh.attn.qk.Ws[i * 32 + sr][sk] = wv[i];
            __syncthreads();
            if (k0 + 64 < 768) {
                #pragma unroll
                for (int i = 0; i < 2; ++i)
                    av[i] = *(const half8*)(A + (size_t)(i * 32 + sr) * 768 + k0 + 64 + sk);
                #pragma unroll
                for (int i = 0; i < 4; ++i)
                    wv[i] = *(const half8*)(W + (size_t)(i * 32 + sr) * 768 + k0 + 64 + sk);
            }
            __builtin_amdgcn_sched_barrier(0);
            #pragma unroll
            for (int kk = 0; kk < 2; ++kk) {
                half8 af = *(const half8*)&sh.attn.qk.As[w * 16 + l16][kk * 32 + quad * 8];
                #pragma unroll
                for (int j = 0; j < 8; ++j) {
                    half8 bf = *(const half8*)&sh.attn.qk.Ws[j * 16 + l16][kk * 32 + quad * 8];
                    acc[j] = __builtin_amdgcn_mfma_f32_16x16x32_f16(af, bf, acc[j], 0, 0, 0);
                }
            }
        }

        __syncthreads();   // all waves done reading qk.As/Ws -> reuse as Ps/Vs

        const float scale = 0.03608439182435161f;   // 1/sqrt(768)
        #pragma unroll
        for (int r = 0; r < 4; ++r) {
            float v[8];
            float mx = -1e30f;
            #pragma unroll
            for (int j = 0; j < 8; ++j) { v[j] = acc[j][r] * scale; mx = fmaxf(mx, v[j]); }
            #pragma unroll
            for (int off = 8; off; off >>= 1) mx = fmaxf(mx, __shfl_xor(mx, off, 16));
            float sum = 0.f;
            #pragma unroll
            for (int j = 0; j < 8; ++j) { v[j] = __expf(v[j] - mx); sum += v[j]; }
            #pragma unroll
            for (int off = 8; off; off >>= 1) sum += __shfl_xor(sum, off, 16);
            const float inv = 1.f / sum;
            const int prow = w * 16 + quad * 4 + r;
            #pragma unroll
            for (int j = 0; j < 8; ++j)
                sh.attn.pv.Ps[prow][j * 16 + l16] = (_Float16)(v[j] * inv);
        }

        // PV: gctx rows [z*256+bm .. +64), cols cg*64.. ; K = 128
        const _Float16* Vt = fa.vT16 + (size_t)z * 768 * 128;
        float*     Cc = fa.bufC + ((size_t)(z * 256 + bm)) * 768;
        _Float16*  Xg = fa.xg16 + ((size_t)(z * 256 + bm)) * 1536 + 768;

        for (int cg = 0; cg < 12; ++cg) {
            __syncthreads();   // Ps ready (first iter) / prior Vs reads done
            {
                const int row = t >> 2;
                const int cb  = (t & 3) * 32;
                const _Float16* vp = Vt + (size_t)(cg * 64 + row) * 128 + cb;
                *(half8*)&sh.attn.pv.Vs[row][cb]      = *(const half8*)(vp);
                *(half8*)&sh.attn.pv.Vs[row][cb + 8]  = *(const half8*)(vp + 8);
                *(half8*)&sh.attn.pv.Vs[row][cb + 16] = *(const half8*)(vp + 16);
                *(half8*)&sh.attn.pv.Vs[row][cb + 24] = *(const half8*)(vp + 24);
            }
            __syncthreads();
            f32x4 a2[4] = {};
            #pragma unroll
            for (int kk = 0; kk < 4; ++kk) {
                half8 af = *(const half8*)&sh.attn.pv.Ps[w * 16 + l16][kk * 32 + quad * 8];
                #pragma unroll
                for (int j = 0; j < 4; ++j) {
                    half8 bf = *(const half8*)&sh.attn.pv.Vs[j * 16 + l16][kk * 32 + quad * 8];
                    a2[j] = __builtin_amdgcn_mfma_f32_16x16x32_f16(af, bf, a2[j], 0, 0, 0);
                }
            }
            #pragma unroll
            for (int j = 0; j < 4; ++j) {
                const int col  = cg * 64 + j * 16 + l16;
                const int row0 = w * 16 + quad * 4;
                #pragma unroll
                for (int r = 0; r < 4; ++r) {
                    const float vv = a2[j][r];
                    Cc[(size_t)(row0 + r) * 768 + col] = vv;
                    Xg[(size_t)(row0 + r) * 1536 + col] = (_Float16)vv;
                }
            }
        }
    }
    grid.sync();

    // ================= phase 3: gate1 — 384 tiles =======================
    for (int tile = blockIdx.x; tile < 384; tile += NBLK) {
        const int by = tile / 12;
        const int bx = tile - by * 12;
        const int bm = by * 64;
        const int bn = bx * 64;
        const _Float16* A = fa.xg16;
        const _Float16* W = fa.Wg116;

        f32x4 acc[4] = {};

        half8 av[2], wv[2];
        #pragma unroll
        for (int i = 0; i < 2; ++i) {
            av[i] = *(const half8*)(A + (size_t)(bm + i * 32 + sr) * 1536 + sk);
            wv[i] = *(const half8*)(W + (size_t)(bn + i * 32 + sr) * 1536 + sk);
        }

        for (int k0 = 0; k0 < 1536; k0 += 64) {
            __syncthreads();
            #pragma unroll
            for (int i = 0; i < 2; ++i) {
                *(half8*)&sh.g.As[i * 32 + sr][sk] = av[i];
                *(half8*)&sh.g.Ws[i * 32 + sr][sk] = wv[i];
            }
            __syncthreads();
            if (k0 + 64 < 1536) {
                #pragma unroll
                for (int i = 0; i < 2; ++i) {
                    av[i] = *(const half8*)(A + (size_t)(bm + i * 32 + sr) * 1536 + k0 + 64 + sk);
                    wv[i] = *(const half8*)(W + (size_t)(bn + i * 32 + sr) * 1536 + k0 + 64 + sk);
                }
            }
            __builtin_amdgcn_sched_barrier(0);
            #pragma unroll
            for (int kk = 0; kk < 2; ++kk) {
                half8 af = *(const half8*)&sh.g.As[w * 16 + l16][kk * 32 + quad * 8];
                #pragma unroll
                for (int j = 0; j < 4; ++j) {
                    half8 bf = *(const half8*)&sh.g.Ws[j * 16 + l16][kk * 32 + quad * 8];
                    acc[j] = __builtin_amdgcn_mfma_f32_16x16x32_f16(af, bf, acc[j], 0, 0, 0);
                }
            }
        }

        #pragma unroll
        for (int j = 0; j < 4; ++j) {
            const int col  = bn + j * 16 + l16;
            const int row0 = bm + w * 16 + quad * 4;
            const float bv = fa.bg1[col];
            #pragma unroll
            for (int r = 0; r < 4; ++r) {
                const size_t off = (size_t)(row0 + r) * 768 + col;
                const float g = sigm(acc[j][r] + bv);
                const float o = g * fa.x[off] + (1.f - g) * fa.bufC[off];
                fa.bufB[off] = o;
                fa.h116[off] = (_Float16)o;
            }
        }
    }
    grid.sync();

    // ================= phase 4: final — 384 tiles =======================
    for (int tile = blockIdx.x; tile < 384; tile += NBLK) {
        const int by = tile / 12;
        const int bx = tile - by * 12;
        const int bm = by * 64;
        const int bn = bx * 64;
        const int bK = (bm >> 8) * 32;
        const _Float16* A = fa.h116;
        const _Float16* W = fa.Wg2a16;

        // stage E and s slices
        #pragma unroll
        for (int i = 0; i < 2; ++i) {
            const int idx = t + i * 256;
            const int k = idx >> 4, c = (idx & 15) * 4;
            *(float4*)&sh.fin.Es[k][c] = *(const float4*)(fa.bufE + (size_t)(bK + k) * 768 + bn + c);
            *(float4*)&sh.fin.Ss[k][c] = *(const float4*)(fa.sIn  + (size_t)(bK + k) * 768 + bn + c);
        }

        f32x4 acc[4] = {};

        half8 av[2], wv[2];
        #pragma unroll
        for (int i = 0; i < 2; ++i) {
            av[i] = *(const half8*)(A + (size_t)(bm + i * 32 + sr) * 768 + sk);
            wv[i] = *(const half8*)(W + (size_t)(bn + i * 32 + sr) * 768 + sk);
        }

        for (int k0 = 0; k0 < 768; k0 += 64) {
            __syncthreads();
            #pragma unroll
            for (int i = 0; i < 2; ++i) {
                *(half8*)&sh.fin.u.a.As[i * 32 + sr][sk] = av[i];
                *(half8*)&sh.fin.u.a.Ws[i * 32 + sr][sk] = wv[i];
            }
            __syncthreads();
            if (k0 + 64 < 768) {
                #pragma unroll
                for (int i = 0; i < 2; ++i) {
                    av[i] = *(const half8*)(A + (size_t)(bm + i * 32 + sr) * 768 + k0 + 64 + sk);
                    wv[i] = *(const half8*)(W + (size_t)(bn + i * 32 + sr) * 768 + k0 + 64 + sk);
                }
            }
            __builtin_amdgcn_sched_barrier(0);
            #pragma unroll
            for (int kk = 0; kk < 2; ++kk) {
                half8 af = *(const half8*)&sh.fin.u.a.As[w * 16 + l16][kk * 32 + quad * 8];
                #pragma unroll
                for (int j = 0; j < 4; ++j) {
                    half8 bf = *(const half8*)&sh.fin.u.a.Ws[j * 16 + l16][kk * 32 + quad * 8];
                    acc[j] = __builtin_amdgcn_mfma_f32_16x16x32_f16(af, bf, acc[j], 0, 0, 0);
                }
            }
        }

        __syncthreads();   // reuse As/Ws as Ds
        #pragma unroll
        for (int j = 0; j < 4; ++j) {
            const int col = j * 16 + l16;
            const float bv = fa.bg2[bn + col];
            #pragma unroll
            for (int r = 0; r < 4; ++r)
                sh.fin.u.Ds[w * 16 + quad * 4 + r][col] = acc[j][r] + bv;
        }
        __syncthreads();

        const int c  = (t & 15) * 4;
        const int r0 = (t >> 4) * 4;
        float4 d4[4], h4v[4];
        #pragma unroll
        for (int rr = 0; rr < 4; ++rr) {
            d4[rr]  = *(const float4*)&sh.fin.u.Ds[r0 + rr][c];
            h4v[rr] = *(const float4*)(fa.bufB + (size_t)(bm + r0 + rr) * 768 + bn + c);
        }
        float* ob = fa.out + (size_t)(bm + r0) * 32 * 768 + bn + c;
        for (int k = 0; k < 32; ++k) {
            const float4 e  = *(const float4*)&sh.fin.Es[k][c];
            const float4 sv = *(const float4*)&sh.fin.Ss[k][c];
            #pragma unroll
            for (int rr = 0; rr < 4; ++rr) {
                float4 o; float g;
                g = sigm(d4[rr].x + e.x); o.x = g * h4v[rr].x + (1.f - g) * sv.x;
                g = sigm(d4[rr].y + e.y); o.y = g * h4v[rr].y + (1.f - g) * sv.y;
                g = sigm(d4[rr].z + e.z); o.z = g * h4v[rr].z + (1.f - g) * sv.z;
                g = sigm(d4[rr].w + e.w); o.w = g * h4v[rr].w + (1.f - g) * sv.w;
                *(float4*)(ob + (size_t)(rr * 32 + k) * 768) = o;
            }
        }
    }
}

extern "C" void kernel_launch(void* const* d_in, const int* in_sizes, int n_in,
                              void* d_out, int out_size, void* d_ws, size_t ws_size,
                              hipStream_t stream) {
    const float* x   = (const float*)d_in[0];
    const float* s   = (const float*)d_in[1];
    const float* g   = (const float*)d_in[2];
    const float* Wq  = (const float*)d_in[3];
    const float* bq  = (const float*)d_in[4];
    const float* Wkv = (const float*)d_in[5];
    const float* bkv = (const float*)d_in[6];
    const float* Wg1 = (const float*)d_in[7];
    const float* bg1 = (const float*)d_in[8];
    const float* Wg2 = (const float*)d_in[9];
    const float* bg2 = (const float*)d_in[10];

    char* w = (char*)d_ws;
    _Float16* xg16   = (_Float16*)(w + 524288);    // [2048][1536]
    _Float16* g16    = (_Float16*)(w + 6815744);   // [1024][768]
    _Float16* s16    = (_Float16*)(w + 8388608);   // [256][768]
    _Float16* q16    = (_Float16*)(w + 8781824);   // [2048][768]
    _Float16* k16    = (_Float16*)(w + 11927552);  // [1024][768]
    _Float16* vT16   = (_Float16*)(w + 13500416);  // [8][768][128]
    _Float16* Wq16   = (_Float16*)(w + 15073280);  // [768][768]
    _Float16* Wkv16  = (_Float16*)(w + 16252928);  // [1536][768]
    _Float16* Wg116  = (_Float16*)(w + 18612224);  // [768][1536]
    _Float16* Wg2a16 = (_Float16*)(w + 20971520);  // [768][768]
    _Float16* Wg2b16 = (_Float16*)(w + 22151168);  // [768][768]
    float*    bufE   = (float*)(w + 23330816);     // [256][768] fp32
    float*    bufC   = (float*)(w + 24117248);     // gctx fp32 [2048][768]
    float*    bufB   = (float*)(w + 30408704);     // h1 fp32 [2048][768]
    _Float16* h116   = (_Float16*)(w + 36700160);  // [2048][768]
    float* out = (float*)d_out;

    FusedArgs fa = {};

    // conv segments
    fa.ca.src[0] = x;         fa.ca.dst[0] = xg16;   fa.ca.sstr[0] = 768;  fa.ca.dstr[0] = 1536; fa.ca.rl[0] = 768;
    fa.ca.src[1] = g;         fa.ca.dst[1] = g16;    fa.ca.sstr[1] = 768;  fa.ca.dstr[1] = 768;  fa.ca.rl[1] = 768;
    fa.ca.src[2] = s;         fa.ca.dst[2] = s16;    fa.ca.sstr[2] = 768;  fa.ca.dstr[2] = 768;  fa.ca.rl[2] = 768;
    fa.ca.src[3] = Wq;        fa.ca.dst[3] = Wq16;   fa.ca.sstr[3] = 768;  fa.ca.dstr[3] = 768;  fa.ca.rl[3] = 768;
    fa.ca.src[4] = Wkv;       fa.ca.dst[4] = Wkv16;  fa.ca.sstr[4] = 768;  fa.ca.dstr[4] = 768;  fa.ca.rl[4] = 768;
    fa.ca.src[5] = Wg1;       fa.ca.dst[5] = Wg116;  fa.ca.sstr[5] = 1536; fa.ca.dstr[5] = 1536; fa.ca.rl[5] = 1536;
    fa.ca.src[6] = Wg2;       fa.ca.dst[6] = Wg2a16; fa.ca.sstr[6] = 1536; fa.ca.dstr[6] = 768;  fa.ca.rl[6] = 768;
    fa.ca.src[7] = Wg2 + 768; fa.ca.dst[7] = Wg2b16; fa.ca.sstr[7] = 1536; fa.ca.dstr[7] = 768;  fa.ca.rl[7] = 768;
    fa.ca.cum[0] = 0;      fa.ca.cum[1] = 196608; fa.ca.cum[2] = 294912; fa.ca.cum[3] = 319488;
    fa.ca.cum[4] = 393216; fa.ca.cum[5] = 540672; fa.ca.cum[6] = 688128; fa.ca.cum[7] = 761856;
    fa.ca.cum[8] = 835584;

    // gemm3 descriptors (64x64 tiles)
    fa.ga.d[0] = { xg16, Wq16,   bq,      (void*)q16,  nullptr,     1536, 768, 0, 12 };  // q:  384 tiles
    fa.ga.d[1] = { g16,  Wkv16,  bkv,     (void*)k16,  (void*)vT16, 768,  768, 1, 24 };  // kv: 384 tiles
    fa.ga.d[2] = { s16,  Wg2b16, nullptr, (void*)bufE, nullptr,     768,  768, 2, 12 };  // E:  48 tiles
    fa.ga.cum[0] = 0; fa.ga.cum[1] = 384; fa.ga.cum[2] = 768; fa.ga.cum[3] = 816;

    fa.q16 = q16; fa.k16 = k16; fa.vT16 = vT16;
    fa.bufC = bufC; fa.xg16 = xg16;
    fa.Wg116 = Wg116; fa.bg1 = bg1; fa.x = x;
    fa.bufB = bufB; fa.h116 = h116;
    fa.Wg2a16 = Wg2a16; fa.bg2 = bg2; fa.bufE = bufE; fa.sIn = s;
    fa.out = out;

    void* kargs[] = { (void*)&fa };
    hipLaunchCooperativeKernel((void*)fused_all, dim3(NBLK), dim3(256), kargs, 0, stream);
}

// Round 7
// 316.946 us; speedup vs baseline: 2.0066x; 2.0066x over previous
//
#include <hip/hip_runtime.h>
#include <math.h>

using half4 = __attribute__((ext_vector_type(4))) _Float16;
using half8 = __attribute__((ext_vector_type(8))) _Float16;
using f32x4 = __attribute__((ext_vector_type(4))) float;

__device__ __forceinline__ float sigm(float z) { return 1.f / (1.f + __expf(-z)); }

// ---------------- multi-segment f32 -> f16 conversion (one dispatch) -----------
struct ConvArgs {
    const float* src[8];
    _Float16*    dst[8];
    int cum[9];
    int sstr[8];
    int dstr[8];
    int rl[8];
};

__global__ __launch_bounds__(256) void conv_multi(ConvArgs a) {
    int c = blockIdx.x * 256 + threadIdx.x;
    if (c >= a.cum[8]) return;
    int s = 0;
    while (c >= a.cum[s + 1]) ++s;
    const int lc  = c - a.cum[s];
    const unsigned cpr = (unsigned)(a.rl[s] >> 3);
    const unsigned row = (unsigned)lc / cpr;
    const int col = (lc - (int)(row * cpr)) * 8;
    const float* sp = a.src[s] + (size_t)row * a.sstr[s] + col;
    float4 v0 = *(const float4*)sp;
    float4 v1 = *(const float4*)(sp + 4);
    half8 h;
    h[0] = (_Float16)v0.x; h[1] = (_Float16)v0.y; h[2] = (_Float16)v0.z; h[3] = (_Float16)v0.w;
    h[4] = (_Float16)v1.x; h[5] = (_Float16)v1.y; h[6] = (_Float16)v1.z; h[7] = (_Float16)v1.w;
    *(half8*)(a.dst[s] + (size_t)row * a.dstr[s] + col) = h;
}

// ======================= 64x64-tile GEMM family, double-buffered ===============
// One __syncthreads per K-iter; loads issued at iter i are LDS-written at i+1
// and consumed by MFMA at i+2 (full-iteration latency cover).

// ---------------- merged 3-way GEMM: q, kv, E in one dispatch ------------------
struct G3Desc {
    const _Float16* A;
    const _Float16* W;
    const float* bias;
    void* o0;
    void* o1;
    int lda, ldw, mode, nbx;   // mode 0: f16 out; 1: kvsplit; 2: f32 out
};
struct G3Args { G3Desc d[3]; int cum[4]; };

__global__ __launch_bounds__(256) void gemm3(G3Args ga) {
    __shared__ _Float16 As[2][64][72];
    __shared__ _Float16 Ws[2][64][72];

    const int t    = threadIdx.x;
    const int w    = t >> 6;
    const int lane = t & 63;
    const int quad = lane >> 4;
    const int l16  = lane & 15;

    int s = 0;
    const int bid = blockIdx.x;
    while (bid >= ga.cum[s + 1]) ++s;
    const int local = bid - ga.cum[s];
    const int nbx   = ga.d[s].nbx;
    const int by    = local / nbx;
    const int bx    = local - by * nbx;
    const int bm    = by * 64;
    const int bn    = bx * 64;
    const _Float16* A = ga.d[s].A;
    const _Float16* W = ga.d[s].W;
    const int lda = ga.d[s].lda;
    const int ldw = ga.d[s].ldw;

    const int sr = t >> 3;
    const int sk = (t & 7) * 8;

    f32x4 acc[4] = {};
    half8 av[2], wv[2];

    // prologue: stage k-tile 0, preload k-tile 1
    #pragma unroll
    for (int i = 0; i < 2; ++i) {
        av[i] = *(const half8*)(A + (size_t)(bm + i * 32 + sr) * lda + sk);
        wv[i] = *(const half8*)(W + (size_t)(bn + i * 32 + sr) * ldw + sk);
    }
    #pragma unroll
    for (int i = 0; i < 2; ++i) {
        *(half8*)&As[0][i * 32 + sr][sk] = av[i];
        *(half8*)&Ws[0][i * 32 + sr][sk] = wv[i];
    }
    #pragma unroll
    for (int i = 0; i < 2; ++i) {
        av[i] = *(const half8*)(A + (size_t)(bm + i * 32 + sr) * lda + 64 + sk);
        wv[i] = *(const half8*)(W + (size_t)(bn + i * 32 + sr) * ldw + 64 + sk);
    }
    __syncthreads();

    for (int it = 0; it < 12; ++it) {
        const int cur = it & 1;
        #pragma unroll
        for (int kk = 0; kk < 2; ++kk) {
            half8 af = *(const half8*)&As[cur][w * 16 + l16][kk * 32 + quad * 8];
            #pragma unroll
            for (int j = 0; j < 4; ++j) {
                half8 bf = *(const half8*)&Ws[cur][j * 16 + l16][kk * 32 + quad * 8];
                acc[j] = __builtin_amdgcn_mfma_f32_16x16x32_f16(af, bf, acc[j], 0, 0, 0);
            }
        }
        if (it + 1 < 12) {
            #pragma unroll
            for (int i = 0; i < 2; ++i) {
                *(half8*)&As[cur ^ 1][i * 32 + sr][sk] = av[i];
                *(half8*)&Ws[cur ^ 1][i * 32 + sr][sk] = wv[i];
            }
        }
        if (it + 2 < 12) {
            #pragma unroll
            for (int i = 0; i < 2; ++i) {
                av[i] = *(const half8*)(A + (size_t)(bm + i * 32 + sr) * lda + (it + 2) * 64 + sk);
                wv[i] = *(const half8*)(W + (size_t)(bn + i * 32 + sr) * ldw + (it + 2) * 64 + sk);
            }
        }
        __syncthreads();
    }

    const int mode = ga.d[s].mode;
    const float* bias = ga.d[s].bias;
    #pragma unroll
    for (int j = 0; j < 4; ++j) {
        const int col  = bn + j * 16 + l16;
        const int row0 = bm + w * 16 + quad * 4;
        const float bv = bias ? bias[col] : 0.f;
        if (mode == 0) {
            _Float16* C2 = (_Float16*)ga.d[s].o0;
            #pragma unroll
            for (int r = 0; r < 4; ++r)
                C2[(size_t)(row0 + r) * 768 + col] = (_Float16)(acc[j][r] + bv);
        } else if (mode == 1) {
            _Float16* K16  = (_Float16*)ga.d[s].o0;
            _Float16* VT16 = (_Float16*)ga.d[s].o1;
            if (col < 768) {
                #pragma unroll
                for (int r = 0; r < 4; ++r)
                    K16[(size_t)(row0 + r) * 768 + col] = (_Float16)(acc[j][r] + bv);
            } else {
                const int b = row0 >> 7, h = col - 768, m0 = row0 & 127;
                half4 hv;
                #pragma unroll
                for (int r = 0; r < 4; ++r) hv[r] = (_Float16)(acc[j][r] + bv);
                *(half4*)(VT16 + ((size_t)(b * 768 + h)) * 128 + m0) = hv;
            }
        } else {
            float* C = (float*)ga.d[s].o0;
            #pragma unroll
            for (int r = 0; r < 4; ++r)
                C[(size_t)(row0 + r) * 768 + col] = acc[j][r] + bv;
        }
    }
}

// ------------- fused attn: scores + softmax + PV (gctx), 32 blocks -------------
// block = 64 q-rows x one batch. P stays in LDS (never touches HBM).
__global__ __launch_bounds__(256) void attn_pv(
    const _Float16* __restrict__ Q, const _Float16* __restrict__ Kt,
    const _Float16* __restrict__ Vt16,
    float* __restrict__ bufC, _Float16* __restrict__ xg16)
{
    __shared__ union {
        struct { _Float16 Qs[2][64][72]; _Float16 Ks[2][128][72]; } qk;   // 55296 B
        struct { _Float16 Ps[64][136]; _Float16 Vs[2][64][136]; } pv;     // 52224 B
    } sh;

    const int t    = threadIdx.x;
    const int w    = t >> 6;
    const int lane = t & 63;
    const int quad = lane >> 4;
    const int l16  = lane & 15;
    const int z    = blockIdx.x >> 2;
    const int bm   = (blockIdx.x & 3) * 64;
    const _Float16* A = Q  + (size_t)z * 256 * 768 + (size_t)bm * 768;
    const _Float16* W = Kt + (size_t)z * 128 * 768;

    const int sr = t >> 3;
    const int sk = (t & 7) * 8;

    f32x4 acc[8] = {};
    half8 av[2], wv[4];

    // prologue
    #pragma unroll
    for (int i = 0; i < 2; ++i)
        av[i] = *(const half8*)(A + (size_t)(i * 32 + sr) * 768 + sk);
    #pragma unroll
    for (int i = 0; i < 4; ++i)
        wv[i] = *(const half8*)(W + (size_t)(i * 32 + sr) * 768 + sk);
    #pragma unroll
    for (int i = 0; i < 2; ++i) *(half8*)&sh.qk.Qs[0][i * 32 + sr][sk] = av[i];
    #pragma unroll
    for (int i = 0; i < 4; ++i) *(half8*)&sh.qk.Ks[0][i * 32 + sr][sk] = wv[i];
    #pragma unroll
    for (int i = 0; i < 2; ++i)
        av[i] = *(const half8*)(A + (size_t)(i * 32 + sr) * 768 + 64 + sk);
    #pragma unroll
    for (int i = 0; i < 4; ++i)
        wv[i] = *(const half8*)(W + (size_t)(i * 32 + sr) * 768 + 64 + sk);
    __syncthreads();

    for (int it = 0; it < 12; ++it) {
        const int cur = it & 1;
        #pragma unroll
        for (int kk = 0; kk < 2; ++kk) {
            half8 af = *(const half8*)&sh.qk.Qs[cur][w * 16 + l16][kk * 32 + quad * 8];
            #pragma unroll
            for (int j = 0; j < 8; ++j) {
                half8 bf = *(const half8*)&sh.qk.Ks[cur][j * 16 + l16][kk * 32 + quad * 8];
                acc[j] = __builtin_amdgcn_mfma_f32_16x16x32_f16(af, bf, acc[j], 0, 0, 0);
            }
        }
        if (it + 1 < 12) {
            #pragma unroll
            for (int i = 0; i < 2; ++i) *(half8*)&sh.qk.Qs[cur ^ 1][i * 32 + sr][sk] = av[i];
            #pragma unroll
            for (int i = 0; i < 4; ++i) *(half8*)&sh.qk.Ks[cur ^ 1][i * 32 + sr][sk] = wv[i];
        }
        if (it + 2 < 12) {
            #pragma unroll
            for (int i = 0; i < 2; ++i)
                av[i] = *(const half8*)(A + (size_t)(i * 32 + sr) * 768 + (it + 2) * 64 + sk);
            #pragma unroll
            for (int i = 0; i < 4; ++i)
                wv[i] = *(const half8*)(W + (size_t)(i * 32 + sr) * 768 + (it + 2) * 64 + sk);
        }
        __syncthreads();
    }

    // softmax into Ps (union reuse: safe, last QK iter ended with a barrier)
    const float scale = 0.03608439182435161f;   // 1/sqrt(768)
    #pragma unroll
    for (int r = 0; r < 4; ++r) {
        float v[8];
        float mx = -1e30f;
        #pragma unroll
        for (int j = 0; j < 8; ++j) { v[j] = acc[j][r] * scale; mx = fmaxf(mx, v[j]); }
        #pragma unroll
        for (int off = 8; off; off >>= 1) mx = fmaxf(mx, __shfl_xor(mx, off, 16));
        float sum = 0.f;
        #pragma unroll
        for (int j = 0; j < 8; ++j) { v[j] = __expf(v[j] - mx); sum += v[j]; }
        #pragma unroll
        for (int off = 8; off; off >>= 1) sum += __shfl_xor(sum, off, 16);
        const float inv = 1.f / sum;
        const int prow = w * 16 + quad * 4 + r;
        #pragma unroll
        for (int j = 0; j < 8; ++j)
            sh.pv.Ps[prow][j * 16 + l16] = (_Float16)(v[j] * inv);
    }

    // PV: gctx[64][768] = P[64][128] @ V^T; V^T staged 64 cols at a time, dbuf
    const _Float16* Vt = Vt16 + (size_t)z * 768 * 128;
    float*     Cc = bufC + ((size_t)(z * 256 + bm)) * 768;
    _Float16*  Xg = xg16 + ((size_t)(z * 256 + bm)) * 1536 + 768;

    const int vrow = t >> 2;
    const int vcb  = (t & 3) * 32;
    half8 vv[4];
    {   // stage cg0 directly, preload cg1 into regs
        const _Float16* vp = Vt + (size_t)vrow * 128 + vcb;
        #pragma unroll
        for (int i = 0; i < 4; ++i)
            *(half8*)&sh.pv.Vs[0][vrow][vcb + i * 8] = *(const half8*)(vp + i * 8);
        const _Float16* vp1 = Vt + (size_t)(64 + vrow) * 128 + vcb;
        #pragma unroll
        for (int i = 0; i < 4; ++i) vv[i] = *(const half8*)(vp1 + i * 8);
    }
    __syncthreads();

    for (int cg = 0; cg < 12; ++cg) {
        const int cur = cg & 1;
        f32x4 a2[4] = {};
        #pragma unroll
        for (int kk = 0; kk < 4; ++kk) {
            half8 af = *(const half8*)&sh.pv.Ps[w * 16 + l16][kk * 32 + quad * 8];
            #pragma unroll
            for (int j = 0; j < 4; ++j) {
                half8 bf = *(const half8*)&sh.pv.Vs[cur][j * 16 + l16][kk * 32 + quad * 8];
                a2[j] = __builtin_amdgcn_mfma_f32_16x16x32_f16(af, bf, a2[j], 0, 0, 0);
            }
        }
        if (cg + 1 < 12) {
            #pragma unroll
            for (int i = 0; i < 4; ++i)
                *(half8*)&sh.pv.Vs[cur ^ 1][vrow][vcb + i * 8] = vv[i];
        }
        if (cg + 2 < 12) {
            const _Float16* vp = Vt + (size_t)((cg + 2) * 64 + vrow) * 128 + vcb;
            #pragma unroll
            for (int i = 0; i < 4; ++i) vv[i] = *(const half8*)(vp + i * 8);
        }
        #pragma unroll
        for (int j = 0; j < 4; ++j) {
            const int col  = cg * 64 + j * 16 + l16;
            const int row0 = w * 16 + quad * 4;
            #pragma unroll
            for (int r = 0; r < 4; ++r) {
                const float vvl = a2[j][r];
                Cc[(size_t)(row0 + r) * 768 + col] = vvl;
                Xg[(size_t)(row0 + r) * 1536 + col] = (_Float16)vvl;
            }
        }
        __syncthreads();
    }
}

// ---------------- t1 GEMM with fused gate1 epilogue ----------------------------
__global__ __launch_bounds__(256) void gemm_gate1(
    const _Float16* __restrict__ A,   // xg16 [2048][1536]
    const _Float16* __restrict__ W,   // Wg116 [768][1536]
    const float* __restrict__ bias,   // bg1
    const float* __restrict__ X,      // x fp32
    const float* __restrict__ GC,     // gctx fp32
    float* __restrict__ H1,
    _Float16* __restrict__ H16)
{
    __shared__ _Float16 As[2][64][72];
    __shared__ _Float16 Ws[2][64][72];

    const int t    = threadIdx.x;
    const int w    = t >> 6;
    const int lane = t & 63;
    const int quad = lane >> 4;
    const int l16  = lane & 15;
    const int bm   = blockIdx.y * 64;
    const int bn   = blockIdx.x * 64;

    const int sr = t >> 3;
    const int sk = (t & 7) * 8;

    f32x4 acc[4] = {};
    half8 av[2], wv[2];

    #pragma unroll
    for (int i = 0; i < 2; ++i) {
        av[i] = *(const half8*)(A + (size_t)(bm + i * 32 + sr) * 1536 + sk);
        wv[i] = *(const half8*)(W + (size_t)(bn + i * 32 + sr) * 1536 + sk);
    }
    #pragma unroll
    for (int i = 0; i < 2; ++i) {
        *(half8*)&As[0][i * 32 + sr][sk] = av[i];
        *(half8*)&Ws[0][i * 32 + sr][sk] = wv[i];
    }
    #pragma unroll
    for (int i = 0; i < 2; ++i) {
        av[i] = *(const half8*)(A + (size_t)(bm + i * 32 + sr) * 1536 + 64 + sk);
        wv[i] = *(const half8*)(W + (size_t)(bn + i * 32 + sr) * 1536 + 64 + sk);
    }
    __syncthreads();

    for (int it = 0; it < 24; ++it) {
        const int cur = it & 1;
        #pragma unroll
        for (int kk = 0; kk < 2; ++kk) {
            half8 af = *(const half8*)&As[cur][w * 16 + l16][kk * 32 + quad * 8];
            #pragma unroll
            for (int j = 0; j < 4; ++j) {
                half8 bf = *(const half8*)&Ws[cur][j * 16 + l16][kk * 32 + quad * 8];
                acc[j] = __builtin_amdgcn_mfma_f32_16x16x32_f16(af, bf, acc[j], 0, 0, 0);
            }
        }
        if (it + 1 < 24) {
            #pragma unroll
            for (int i = 0; i < 2; ++i) {
                *(half8*)&As[cur ^ 1][i * 32 + sr][sk] = av[i];
                *(half8*)&Ws[cur ^ 1][i * 32 + sr][sk] = wv[i];
            }
        }
        if (it + 2 < 24) {
            #pragma unroll
            for (int i = 0; i < 2; ++i) {
                av[i] = *(const half8*)(A + (size_t)(bm + i * 32 + sr) * 1536 + (it + 2) * 64 + sk);
                wv[i] = *(const half8*)(W + (size_t)(bn + i * 32 + sr) * 1536 + (it + 2) * 64 + sk);
            }
        }
        __syncthreads();
    }

    #pragma unroll
    for (int j = 0; j < 4; ++j) {
        const int col  = bn + j * 16 + l16;
        const int row0 = bm + w * 16 + quad * 4;
        const float bv = bias[col];
        #pragma unroll
        for (int r = 0; r < 4; ++r) {
            const size_t off = (size_t)(row0 + r) * 768 + col;
            const float g = sigm(acc[j][r] + bv);
            const float o = g * X[off] + (1.f - g) * GC[off];
            H1[off]  = o;
            H16[off] = (_Float16)o;
        }
    }
}

// ---------------- D GEMM with fused final_combine epilogue ---------------------
__global__ __launch_bounds__(256) void gemm_final(
    const _Float16* __restrict__ A,   // h116 [2048][768]
    const _Float16* __restrict__ W,   // Wg2a16 [768][768]
    const float* __restrict__ bias,   // bg2
    const float* __restrict__ Ebuf,   // [256][768] fp32
    const float* __restrict__ Sbuf,   // s fp32 [256][768]
    const float* __restrict__ H1,     // h1 fp32 [2048][768]
    float* __restrict__ out)
{
    __shared__ union {
        struct { _Float16 As[2][64][72]; _Float16 Ws[2][64][72]; } a;   // 36864 B
        float Ds[64][76];                                               // 19456 B
    } u;
    __shared__ float Es[32][64];
    __shared__ float Ss[32][64];

    const int t    = threadIdx.x;
    const int w    = t >> 6;
    const int lane = t & 63;
    const int quad = lane >> 4;
    const int l16  = lane & 15;
    const int bm   = blockIdx.y * 64;
    const int bn   = blockIdx.x * 64;
    const int bK   = (bm >> 8) * 32;

    const int sr = t >> 3;
    const int sk = (t & 7) * 8;

    // stage E and s slices
    #pragma unroll
    for (int i = 0; i < 2; ++i) {
        const int idx = t + i * 256;
        const int k = idx >> 4, c = (idx & 15) * 4;
        *(float4*)&Es[k][c] = *(const float4*)(Ebuf + (size_t)(bK + k) * 768 + bn + c);
        *(float4*)&Ss[k][c] = *(const float4*)(Sbuf + (size_t)(bK + k) * 768 + bn + c);
    }

    f32x4 acc[4] = {};
    half8 av[2], wv[2];

    #pragma unroll
    for (int i = 0; i < 2; ++i) {
        av[i] = *(const half8*)(A + (size_t)(bm + i * 32 + sr) * 768 + sk);
        wv[i] = *(const half8*)(W + (size_t)(bn + i * 32 + sr) * 768 + sk);
    }
    #pragma unroll
    for (int i = 0; i < 2; ++i) {
        *(half8*)&u.a.As[0][i * 32 + sr][sk] = av[i];
        *(half8*)&u.a.Ws[0][i * 32 + sr][sk] = wv[i];
    }
    #pragma unroll
    for (int i = 0; i < 2; ++i) {
        av[i] = *(const half8*)(A + (size_t)(bm + i * 32 + sr) * 768 + 64 + sk);
        wv[i] = *(const half8*)(W + (size_t)(bn + i * 32 + sr) * 768 + 64 + sk);
    }
    __syncthreads();

    for (int it = 0; it < 12; ++it) {
        const int cur = it & 1;
        #pragma unroll
        for (int kk = 0; kk < 2; ++kk) {
            half8 af = *(const half8*)&u.a.As[cur][w * 16 + l16][kk * 32 + quad * 8];
            #pragma unroll
            for (int j = 0; j < 4; ++j) {
                half8 bf = *(const half8*)&u.a.Ws[cur][j * 16 + l16][kk * 32 + quad * 8];
                acc[j] = __builtin_amdgcn_mfma_f32_16x16x32_f16(af, bf, acc[j], 0, 0, 0);
            }
        }
        if (it + 1 < 12) {
            #pragma unroll
            for (int i = 0; i < 2; ++i) {
                *(half8*)&u.a.As[cur ^ 1][i * 32 + sr][sk] = av[i];
                *(half8*)&u.a.Ws[cur ^ 1][i * 32 + sr][sk] = wv[i];
            }
        }
        if (it + 2 < 12) {
            #pragma unroll
            for (int i = 0; i < 2; ++i) {
                av[i] = *(const half8*)(A + (size_t)(bm + i * 32 + sr) * 768 + (it + 2) * 64 + sk);
                wv[i] = *(const half8*)(W + (size_t)(bn + i * 32 + sr) * 768 + (it + 2) * 64 + sk);
            }
        }
        __syncthreads();
    }

    // union reuse: last K-iter ended with barrier
    #pragma unroll
    for (int j = 0; j < 4; ++j) {
        const int col = j * 16 + l16;
        const float bv = bias[bn + col];
        #pragma unroll
        for (int r = 0; r < 4; ++r)
            u.Ds[w * 16 + quad * 4 + r][col] = acc[j][r] + bv;
    }
    __syncthreads();

    const int c  = (t & 15) * 4;
    const int r0 = (t >> 4) * 4;
    float4 d4[4], h4v[4];
    #pragma unroll
    for (int rr = 0; rr < 4; ++rr) {
        d4[rr]  = *(const float4*)&u.Ds[r0 + rr][c];
        h4v[rr] = *(const float4*)(H1 + (size_t)(bm + r0 + rr) * 768 + bn + c);
    }
    float* ob = out + (size_t)(bm + r0) * 32 * 768 + bn + c;
    for (int k = 0; k < 32; ++k) {
        const float4 e  = *(const float4*)&Es[k][c];
        const float4 sv = *(const float4*)&Ss[k][c];
        #pragma unroll
        for (int rr = 0; rr < 4; ++rr) {
            float4 o; float g;
            g = sigm(d4[rr].x + e.x); o.x = g * h4v[rr].x + (1.f - g) * sv.x;
            g = sigm(d4[rr].y + e.y); o.y = g * h4v[rr].y + (1.f - g) * sv.y;
            g = sigm(d4[rr].z + e.z); o.z = g * h4v[rr].z + (1.f - g) * sv.z;
            g = sigm(d4[rr].w + e.w); o.w = g * h4v[rr].w + (1.f - g) * sv.w;
            *(float4*)(ob + (size_t)(rr * 32 + k) * 768) = o;
        }
    }
}

extern "C" void kernel_launch(void* const* d_in, const int* in_sizes, int n_in,
                              void* d_out, int out_size, void* d_ws, size_t ws_size,
                              hipStream_t stream) {
    const float* x   = (const float*)d_in[0];
    const float* s   = (const float*)d_in[1];
    const float* g   = (const float*)d_in[2];
    const float* Wq  = (const float*)d_in[3];
    const float* bq  = (const float*)d_in[4];
    const float* Wkv = (const float*)d_in[5];
    const float* bkv = (const float*)d_in[6];
    const float* Wg1 = (const float*)d_in[7];
    const float* bg1 = (const float*)d_in[8];
    const float* Wg2 = (const float*)d_in[9];
    const float* bg2 = (const float*)d_in[10];

    char* w = (char*)d_ws;
    _Float16* xg16   = (_Float16*)(w + 524288);    // [2048][1536]
    _Float16* g16    = (_Float16*)(w + 6815744);   // [1024][768]
    _Float16* s16    = (_Float16*)(w + 8388608);   // [256][768]
    _Float16* q16    = (_Float16*)(w + 8781824);   // [2048][768]
    _Float16* k16    = (_Float16*)(w + 11927552);  // [1024][768]
    _Float16* vT16   = (_Float16*)(w + 13500416);  // [8][768][128]
    _Float16* Wq16   = (_Float16*)(w + 15073280);  // [768][768]
    _Float16* Wkv16  = (_Float16*)(w + 16252928);  // [1536][768]
    _Float16* Wg116  = (_Float16*)(w + 18612224);  // [768][1536]
    _Float16* Wg2a16 = (_Float16*)(w + 20971520);  // [768][768]
    _Float16* Wg2b16 = (_Float16*)(w + 22151168);  // [768][768]
    float*    bufE   = (float*)(w + 23330816);     // [256][768] fp32
    float*    bufC   = (float*)(w + 24117248);     // gctx fp32 [2048][768]
    float*    bufB   = (float*)(w + 30408704);     // h1 fp32 [2048][768]
    _Float16* h116   = (_Float16*)(w + 36700160);  // [2048][768]
    float* out = (float*)d_out;

    const dim3 blk(256);

    // 1) all f32->f16 conversions
    ConvArgs ca;
    ca.src[0] = x;         ca.dst[0] = xg16;   ca.sstr[0] = 768;  ca.dstr[0] = 1536; ca.rl[0] = 768;
    ca.src[1] = g;         ca.dst[1] = g16;    ca.sstr[1] = 768;  ca.dstr[1] = 768;  ca.rl[1] = 768;
    ca.src[2] = s;         ca.dst[2] = s16;    ca.sstr[2] = 768;  ca.dstr[2] = 768;  ca.rl[2] = 768;
    ca.src[3] = Wq;        ca.dst[3] = Wq16;   ca.sstr[3] = 768;  ca.dstr[3] = 768;  ca.rl[3] = 768;
    ca.src[4] = Wkv;       ca.dst[4] = Wkv16;  ca.sstr[4] = 768;  ca.dstr[4] = 768;  ca.rl[4] = 768;
    ca.src[5] = Wg1;       ca.dst[5] = Wg116;  ca.sstr[5] = 1536; ca.dstr[5] = 1536; ca.rl[5] = 1536;
    ca.src[6] = Wg2;       ca.dst[6] = Wg2a16; ca.sstr[6] = 1536; ca.dstr[6] = 768;  ca.rl[6] = 768;
    ca.src[7] = Wg2 + 768; ca.dst[7] = Wg2b16; ca.sstr[7] = 1536; ca.dstr[7] = 768;  ca.rl[7] = 768;
    ca.cum[0] = 0;      ca.cum[1] = 196608; ca.cum[2] = 294912; ca.cum[3] = 319488;
    ca.cum[4] = 393216; ca.cum[5] = 540672; ca.cum[6] = 688128; ca.cum[7] = 761856;
    ca.cum[8] = 835584;
    conv_multi<<<dim3(3264), blk, 0, stream>>>(ca);

    // 2) q16, {k16,vT16}, E in one dispatch (64x64 tiles: 816 blocks)
    G3Args ga = {};
    ga.d[0] = { xg16, Wq16,   bq,      (void*)q16,  nullptr,     1536, 768, 0, 12 };
    ga.d[1] = { g16,  Wkv16,  bkv,     (void*)k16,  (void*)vT16, 768,  768, 1, 24 };
    ga.d[2] = { s16,  Wg2b16, nullptr, (void*)bufE, nullptr,     768,  768, 2, 12 };
    ga.cum[0] = 0; ga.cum[1] = 384; ga.cum[2] = 768; ga.cum[3] = 816;
    gemm3<<<dim3(816), blk, 0, stream>>>(ga);

    // 3) attn scores + softmax + PV fused -> bufC fp32 + xg16 cols 768..
    attn_pv<<<dim3(32), blk, 0, stream>>>(q16, k16, vT16, bufC, xg16);

    // 4) t1 = [x|gctx] @ Wg1^T + bg1, fused gate1 -> bufB (h1) + h116
    gemm_gate1<<<dim3(12, 32), blk, 0, stream>>>(
        xg16, Wg116, bg1, x, bufC, bufB, h116);

    // 5) D = h1 @ Wg2a^T + bg2, fused final combine -> out
    gemm_final<<<dim3(12, 32), blk, 0, stream>>>(
        h116, Wg2a16, bg2, bufE, s, bufB, out);
}